// Round 6
// baseline (19236.543 us; speedup 1.0000x reference)
//
#include <hip/hip_runtime.h>

typedef _Float16 f16;
typedef _Float16 f16x8 __attribute__((ext_vector_type(8)));
typedef float    f32x4 __attribute__((ext_vector_type(4)));
typedef unsigned int u32x4 __attribute__((ext_vector_type(4)));

static __device__ __forceinline__ f16x8 asf16x8(u32x4 v) {
  return __builtin_bit_cast(f16x8, v);
}

struct PtrPack { const float* p[8]; };

// ---------------- prep A: 4x Wx (256x256) fp32 [k][u] -> f16 [u][k] for the GEMM ----
__global__ __launch_bounds__(256) void k_prep(PtrPack pp, f16* __restrict__ wxT) {
  int m = blockIdx.z, kt = blockIdx.y, ut = blockIdx.x;
  const float* src = pp.p[m];
  f16* dst = wxT + m * 65536;
  __shared__ f16 tile[64][66];
  int c = threadIdx.x & 63, r0 = threadIdx.x >> 6;
#pragma unroll
  for (int i = 0; i < 16; ++i) {
    int r = i * 4 + r0;
    tile[c][r] = (f16)src[(kt * 64 + r) * 256 + ut * 64 + c];
  }
  __syncthreads();
#pragma unroll
  for (int i = 0; i < 16; ++i) {
    int ul = i * 4 + r0;
    dst[(size_t)(ut * 64 + ul) * 256 + kt * 64 + c] = tile[ul][c];
  }
}

// ---------------- prep F: 4x Wh fp32 [k][u] -> MFMA B-fragment-major f16 -------------
// frag(ct,kt): 64 lanes x 16B; lane l holds Wh[k=kt*32+(l>>4)*8+e][col=ct*16+(l&15)].
// One coalesced 1KB b128 load delivers a whole fragment to a wave.
__global__ __launch_bounds__(256) void k_prepF(PtrPack pp, u32x4* __restrict__ fragB) {
  int kb = blockIdx.x;   // k-block of 64 (0..3)
  int m  = blockIdx.y;   // gate 0..3 = i,f,g,o
  const float* src = pp.p[4 + m];
  int u = threadIdx.x;
  int ct = m * 16 + (u >> 4), cl = u & 15;
#pragma unroll
  for (int q = 0; q < 2; ++q) {
    int kt = kb * 2 + q;
#pragma unroll
    for (int l16 = 0; l16 < 4; ++l16) {
      union { f16 h[8]; u32x4 v; } pk;
#pragma unroll
      for (int e = 0; e < 8; ++e)
        pk.h[e] = (f16)src[(size_t)(kt * 32 + l16 * 8 + e) * 256 + u];
      fragB[(size_t)((ct * 8 + kt) * 64 + l16 * 16 + cl)] = pk.v;
    }
  }
}

// ---------------- X-part GEMM: XW (f16, layout [t][b][u][gate]) ----------------------
__global__ __launch_bounds__(256) void k_gemm(const float* __restrict__ X,
                                              const f16* __restrict__ wxT,
                                              f16* __restrict__ xw, int chunk0) {
  int nblk = blockIdx.x;  // gate
  int mblk = blockIdx.y;
  int b    = blockIdx.z;
  __shared__ f16 Alds[64][48];
  __shared__ f16 Blds[256][48];
  int tid = threadIdx.x, wave = tid >> 6, lane = tid & 63;
  int l15 = lane & 15, l4 = lane >> 4;
  f32x4 acc[16];
#pragma unroll
  for (int i = 0; i < 16; ++i) acc[i] = (f32x4){0.f, 0.f, 0.f, 0.f};
  const float* Xb = X + ((size_t)b * 2048 + chunk0 + mblk * 64) * 256;
  const f16*   Bb = wxT + (size_t)nblk * 256 * 256;
  int arow = tid >> 2, akq = (tid & 3) * 8;

  for (int kk = 0; kk < 8; ++kk) {
    {
      const float* s = Xb + arow * 256 + kk * 32 + akq;
      float4 v0 = *(const float4*)s;
      float4 v1 = *(const float4*)(s + 4);
      union { f16 h[8]; uint4 q; } uq;
      uq.h[0] = (f16)v0.x; uq.h[1] = (f16)v0.y; uq.h[2] = (f16)v0.z; uq.h[3] = (f16)v0.w;
      uq.h[4] = (f16)v1.x; uq.h[5] = (f16)v1.y; uq.h[6] = (f16)v1.z; uq.h[7] = (f16)v1.w;
      *(uint4*)(&Alds[arow][akq]) = uq.q;
    }
    {
      const uint4* s = (const uint4*)(Bb + (size_t)tid * 256 + kk * 32);
      uint4* d = (uint4*)(&Blds[tid][0]);
      d[0] = s[0]; d[1] = s[1]; d[2] = s[2]; d[3] = s[3];
    }
    __syncthreads();
    f16x8 a = *(const f16x8*)(&Alds[wave * 16 + l15][l4 * 8]);
#pragma unroll
    for (int nt = 0; nt < 16; ++nt) {
      f16x8 bb = *(const f16x8*)(&Blds[nt * 16 + l15][l4 * 8]);
      acc[nt] = __builtin_amdgcn_mfma_f32_16x16x32_f16(a, bb, acc[nt], 0, 0, 0);
    }
    __syncthreads();
  }
#pragma unroll
  for (int nt = 0; nt < 16; ++nt) {
#pragma unroll
    for (int r = 0; r < 4; ++r) {
      int trow = mblk * 64 + wave * 16 + l4 * 4 + r;
      int ucol = nt * 16 + l15;
      xw[((size_t)trow * 64 + b) * 1024 + ucol * 4 + nblk] = (f16)acc[nt][r];
    }
  }
}

// ---------------- recurrent kernel: MFMA h-matmul, 1 wg/batch, 512 thr ---------------
// Wave w owns units [w*32, w*32+32): output col-tiles ct = G*16 + w*2 + d (d=0,1).
// A = h broadcast to all 16 rows (all C rows equal). Gates i,f pinned in 128 VGPRs;
// gates g,o streamed from L2 (1KB coalesced per fragment). In-wave epilogue, 1 barrier.
__global__ __launch_bounds__(512, 1) void k_rnn(
    const f16* __restrict__ xw, const u32x4* __restrict__ fragB,
    const float* __restrict__ bi, const float* __restrict__ bf_,
    const float* __restrict__ bg, const float* __restrict__ bo,
    float* __restrict__ out, float* __restrict__ hstate, float* __restrict__ cstate,
    int chunk0, int chunk_len) {
  __shared__ unsigned short hb[2][256];
  int b = blockIdx.x;
  int tid = threadIdx.x;
  int w = tid >> 6, lane = tid & 63;
  int ul = lane & 31;
  int u = w * 32 + ul;
  bool act = lane < 32;

  // persistent B fragments for gates i (R0) and f (R1): [d*8 + kt]
  u32x4 R0[16], R1[16];
#pragma unroll
  for (int d = 0; d < 2; ++d)
#pragma unroll
    for (int kt = 0; kt < 8; ++kt) {
      R0[d * 8 + kt] = fragB[(size_t)((( 0 + w * 2 + d) * 8 + kt) * 64 + lane)];
      R1[d * 8 + kt] = fragB[(size_t)(((16 + w * 2 + d) * 8 + kt) * 64 + lane)];
    }

  float B0 = bi[u], B1 = bf_[u], B2 = bg[u], B3 = bo[u];
  float c, hcur;
  if (chunk0 == 0) { c = 0.f; hcur = 0.f; }
  else { c = cstate[b * 256 + u]; hcur = hstate[b * 256 + u]; }
  if (act) hb[0][u] = __builtin_bit_cast(unsigned short, (f16)hcur);
  __syncthreads();

  int p = 0;
#pragma unroll 1
  for (int t = 0; t < chunk_len; ++t) {
    // keep persistent fragments resident (no remat, no sink)
#pragma unroll
    for (int j = 0; j < 16; ++j) {
      asm volatile("" : "+v"(R0[j]));
      asm volatile("" : "+v"(R1[j]));
    }
    // x-part for this step (one 8B coalesced load per lane)
    ushort4 xv = *(const ushort4*)(xw + (((size_t)t * 64 + b) * 256 + u) * 4);
    // A fragments: h broadcast; lane l reads h[(l>>4)*8 .. +8] per k-tile
    u32x4 A[8];
    {
      const char* hbase = (const char*)(&hb[p][0]) + ((lane >> 4) * 16);
#pragma unroll
      for (int kt = 0; kt < 8; ++kt) A[kt] = *(const u32x4*)(hbase + kt * 64);
    }
    // stream gate g fragments (consumed after i,f compute; latency hides under MFMA)
    u32x4 S[16];
#pragma unroll
    for (int d = 0; d < 2; ++d)
#pragma unroll
      for (int kt = 0; kt < 8; ++kt)
        S[d * 8 + kt] = fragB[(size_t)(((32 + w * 2 + d) * 8 + kt) * 64 + lane)];

    f32x4 a0, a1;
    // gate i from R0
    a0 = (f32x4){0.f, 0.f, 0.f, 0.f}; a1 = (f32x4){0.f, 0.f, 0.f, 0.f};
#pragma unroll
    for (int kt = 0; kt < 8; ++kt) {
      a0 = __builtin_amdgcn_mfma_f32_16x16x32_f16(asf16x8(A[kt]), asf16x8(R0[kt]), a0, 0, 0, 0);
      a1 = __builtin_amdgcn_mfma_f32_16x16x32_f16(asf16x8(A[kt]), asf16x8(R0[8 + kt]), a1, 0, 0, 0);
    }
    float gi0 = a0[0], gi1 = a1[0];
    // gate f from R1
    a0 = (f32x4){0.f, 0.f, 0.f, 0.f}; a1 = (f32x4){0.f, 0.f, 0.f, 0.f};
#pragma unroll
    for (int kt = 0; kt < 8; ++kt) {
      a0 = __builtin_amdgcn_mfma_f32_16x16x32_f16(asf16x8(A[kt]), asf16x8(R1[kt]), a0, 0, 0, 0);
      a1 = __builtin_amdgcn_mfma_f32_16x16x32_f16(asf16x8(A[kt]), asf16x8(R1[8 + kt]), a1, 0, 0, 0);
    }
    float gf0 = a0[0], gf1 = a1[0];
    // gate g from S
    a0 = (f32x4){0.f, 0.f, 0.f, 0.f}; a1 = (f32x4){0.f, 0.f, 0.f, 0.f};
#pragma unroll
    for (int kt = 0; kt < 8; ++kt) {
      a0 = __builtin_amdgcn_mfma_f32_16x16x32_f16(asf16x8(A[kt]), asf16x8(S[kt]), a0, 0, 0, 0);
      a1 = __builtin_amdgcn_mfma_f32_16x16x32_f16(asf16x8(A[kt]), asf16x8(S[8 + kt]), a1, 0, 0, 0);
    }
    float gg0 = a0[0], gg1 = a1[0];
    // no-reorder fence: keep gate-o loads below gate-g consumption (caps live regs)
    __builtin_amdgcn_sched_barrier(0);
    // stream gate o fragments (reuse S)
#pragma unroll
    for (int d = 0; d < 2; ++d)
#pragma unroll
      for (int kt = 0; kt < 8; ++kt)
        S[d * 8 + kt] = fragB[(size_t)(((48 + w * 2 + d) * 8 + kt) * 64 + lane)];
    a0 = (f32x4){0.f, 0.f, 0.f, 0.f}; a1 = (f32x4){0.f, 0.f, 0.f, 0.f};
#pragma unroll
    for (int kt = 0; kt < 8; ++kt) {
      a0 = __builtin_amdgcn_mfma_f32_16x16x32_f16(asf16x8(A[kt]), asf16x8(S[kt]), a0, 0, 0, 0);
      a1 = __builtin_amdgcn_mfma_f32_16x16x32_f16(asf16x8(A[kt]), asf16x8(S[8 + kt]), a1, 0, 0, 0);
    }
    float go0 = a0[0], go1 = a1[0];

    // in-wave epilogue: lane<32 owns unit u = w*32+lane; d-select via lane bit 4
    bool dsel = (lane & 16) != 0;
    float xi = (float)__builtin_bit_cast(f16, xv.x);
    float xf = (float)__builtin_bit_cast(f16, xv.y);
    float xg = (float)__builtin_bit_cast(f16, xv.z);
    float xo = (float)__builtin_bit_cast(f16, xv.w);
    float pi_ = (dsel ? gi1 : gi0) + xi + B0;
    float pf_ = (dsel ? gf1 : gf0) + xf + B1;
    float pg_ = (dsel ? gg1 : gg0) + xg + B2;
    float po_ = (dsel ? go1 : go0) + xo + B3;
    float Gi = 1.f / (1.f + __expf(-pi_));
    float Gf = 1.f / (1.f + __expf(-pf_));
    float e2 = __expf(-2.f * fabsf(pg_));
    float Gg = copysignf((1.f - e2) / (1.f + e2), pg_);
    float Go = 1.f / (1.f + __expf(-po_));
    c = Gf * c + Gi * Gg;
    float ec = __expf(-2.f * fabsf(c));
    float tc = copysignf((1.f - ec) / (1.f + ec), c);
    float h = Go * tc;
    hcur = h;
    int gt = chunk0 + t;
    if (act) {
      out[((size_t)b * 2048 + gt) * 256 + u] = h;
      hb[p ^ 1][u] = __builtin_bit_cast(unsigned short, (f16)h);
      if (gt == 2047) {
        out[33554432 + b * 256 + u] = h;
        out[33554432 + 16384 + b * 256 + u] = c;
      }
    }
    __syncthreads();
    p ^= 1;
  }
  if ((chunk0 + chunk_len < 2048) && act) {
    hstate[b * 256 + u] = hcur;
    cstate[b * 256 + u] = c;
  }
}

extern "C" void kernel_launch(void* const* d_in, const int* in_sizes, int n_in,
                              void* d_out, int out_size, void* d_ws, size_t ws_size,
                              hipStream_t stream) {
  const float* X = (const float*)d_in[0];
  // dict order: X, W_ii, W_hi, b_i, W_if, W_hf, b_f, W_ig, W_hg, b_g, W_io, W_ho, b_o
  PtrPack pp;
  pp.p[0] = (const float*)d_in[1];   // W_ii
  pp.p[1] = (const float*)d_in[4];   // W_if
  pp.p[2] = (const float*)d_in[7];   // W_ig
  pp.p[3] = (const float*)d_in[10];  // W_io
  pp.p[4] = (const float*)d_in[2];   // W_hi
  pp.p[5] = (const float*)d_in[5];   // W_hf
  pp.p[6] = (const float*)d_in[8];   // W_hg
  pp.p[7] = (const float*)d_in[11];  // W_ho
  const float* bi  = (const float*)d_in[3];
  const float* bf_ = (const float*)d_in[6];
  const float* bg  = (const float*)d_in[9];
  const float* bo  = (const float*)d_in[12];
  float* out = (float*)d_out;

  char* ws = (char*)d_ws;
  f16*   wxT    = (f16*)ws;                       // 524288 B
  u32x4* fragB  = (u32x4*)(ws + 524288);          // 524288 B (4 gates x 16 ct x 8 kt x 1KB)
  float* hstate = (float*)(ws + 1048576);         // 65536 B
  float* cstate = (float*)(ws + 1114112);         // 65536 B
  f16*   xwbuf  = (f16*)(ws + 1179648);           // S_c * 64 * 1024 * 2 B

  long avail = (ws_size > 1310720) ? (long)(ws_size - 1310720) : 0;
  long sc = avail / 131072;
  sc = (sc / 64) * 64;
  if (sc < 64) sc = 64;
  if (sc > 2048) sc = 2048;

  k_prep<<<dim3(4, 4, 4), 256, 0, stream>>>(pp, wxT);
  k_prepF<<<dim3(4, 4), 256, 0, stream>>>(pp, fragB);

  for (int s0 = 0; s0 < 2048; s0 += (int)sc) {
    int len = (int)((2048 - s0) < sc ? (2048 - s0) : sc);
    k_gemm<<<dim3(4, len / 64, 64), 256, 0, stream>>>(X, wxT, xwbuf, s0);
    k_rnn<<<dim3(64), 512, 0, stream>>>(xwbuf, fragB, bi, bf_, bg, bo, out,
                                        hstate, cstate, s0, len);
  }
}